// Round 8
// baseline (273.645 us; speedup 1.0000x reference)
//
#include <hip/hip_runtime.h>

#define N_NODES 80000
#define N_EDGES 1280000
#define IN_CH 128
#define HID 64
#define OUT_CH 32

#define NBUCK 625      // 128 dst-nodes per bucket; 625*128 == 80000
#define CAP 3072       // bucket capacity; Poisson(mean=2048) -> +20 sigma safe
#define BIN_BLOCKS 256

typedef float vf2 __attribute__((ext_vector_type(2)));
typedef float vf4 __attribute__((ext_vector_type(4)));

// ---- bf16 pack/unpack helpers (RNE) ----
__device__ __forceinline__ float bl(unsigned u) { return __uint_as_float(u << 16); }
__device__ __forceinline__ float bh(unsigned u) { return __uint_as_float(u & 0xFFFF0000u); }
__device__ __forceinline__ unsigned bf16rn(float x) {
    unsigned u = __float_as_uint(x);
    return (u + 0x7FFFu + ((u >> 16) & 1u)) >> 16;
}
__device__ __forceinline__ unsigned pack2(float a, float b) {
    return bf16rn(a) | (bf16rn(b) << 16);
}

// ---------------- pass 1: bin edges by dst bucket ----------------
// packed word: src (17 bits) | dstLocal (7 bits) << 17
__global__ __launch_bounds__(256) void k_bin(const int* __restrict__ src,
                                             const int* __restrict__ dst,
                                             int* __restrict__ gcur,
                                             unsigned int* __restrict__ binned) {
    __shared__ int hist[NBUCK];
    __shared__ int lcur[NBUCK];
    int t = threadIdx.x;
    const int chunk = N_EDGES / BIN_BLOCKS;  // 5000
    int e0 = blockIdx.x * chunk;
    int e1 = e0 + chunk;
    for (int i = t; i < NBUCK; i += 256) hist[i] = 0;
    __syncthreads();
    for (int e = e0 + t; e < e1; e += 256)
        atomicAdd(&hist[dst[e] >> 7], 1);
    __syncthreads();
    for (int i = t; i < NBUCK; i += 256) {
        int h = hist[i];
        lcur[i] = h ? atomicAdd(&gcur[i], h) : 0;
    }
    __syncthreads();
    for (int e = e0 + t; e < e1; e += 256) {
        int d = dst[e];
        int bk = d >> 7;
        int pos = atomicAdd(&lcur[bk], 1);
        if (pos < CAP)
            binned[(size_t)bk * CAP + pos] =
                (unsigned int)src[e] | ((unsigned int)(d & 127) << 17);
    }
}

// ---------------- fused: CSR build (blocks 0..624) + GEMM1 (blocks 625..1249) ----
// CSR: per-bucket counting sort -> csr (src only), rs/re, dinv
// GEMM1: h1[n][:] = x[n] @ W1 (UNSCALED), bf16, feature-split into two tables
// h1a (cols 0..31) and h1b (cols 32..63), each [N][16] uints = 5.12 MB.
__global__ __launch_bounds__(256) void k_csr_gemm1(
        const unsigned int* __restrict__ binned, const int* __restrict__ cnt,
        int* __restrict__ csr, int* __restrict__ rs, int* __restrict__ re,
        float* __restrict__ dinv,
        const float* __restrict__ x, const float* __restrict__ W1,
        unsigned int* __restrict__ h1a, unsigned int* __restrict__ h1b) {
    __shared__ float smem[12800];  // 51200 B: sX 128x68 (8704 f) + sW 64x64 (4096 f)
    int bid = blockIdx.x, t = threadIdx.x;
    if (bid < NBUCK) {
        // ---- CSR path ----
        int* deg = (int*)smem;
        int* scan = deg + 128;
        int* cur = scan + 128;
        int bk = bid;
        int n_e = min(cnt[bk], CAP);
        const unsigned int* eb = binned + (size_t)bk * CAP;
        if (t < 128) deg[t] = 0;
        __syncthreads();
        for (int i = t; i < n_e; i += 256) atomicAdd(&deg[eb[i] >> 17], 1);
        __syncthreads();
        if (t < 128) scan[t] = deg[t];
        __syncthreads();
        for (int off = 1; off < 128; off <<= 1) {
            int v = (t < 128 && t >= off) ? scan[t - off] : 0;
            __syncthreads();
            if (t < 128) scan[t] += v;
            __syncthreads();
        }
        if (t < 128) {
            int incl = scan[t];
            int s = incl - deg[t];
            cur[t] = s;
            int n = bk * 128 + t;
            int base = bk * CAP;
            rs[n] = base + s;
            re[n] = base + incl;
            dinv[n] = rsqrtf((float)(deg[t] + 1));  // +1 self loop
        }
        __syncthreads();
        for (int i = t; i < n_e; i += 256) {
            unsigned int p = eb[i];
            int dL = p >> 17;
            int pos = atomicAdd(&cur[dL], 1);
            csr[bk * CAP + pos] = (int)(p & 0x1FFFF);
        }
    } else {
        // ---- GEMM1 path: 128 nodes/block, 4 nodes x 8 cols per thread ----
        float* sX = smem;             // 128 x 68
        float* sW = smem + 128 * 68;  // 64 x 64
        long long nb = (long long)(bid - NBUCK) * 128;
        int tx2 = t & 31, tc = t >> 5;     // nodes {tx2+32i}, cols tc*8..tc*8+7
        float acc[4][8];
#pragma unroll
        for (int i = 0; i < 4; ++i)
#pragma unroll
            for (int c = 0; c < 8; ++c) acc[i][c] = 0.f;
        for (int H = 0; H < 2; ++H) {
            int k0 = H * 64;
            __syncthreads();
#pragma unroll
            for (int r = 0; r < 8; ++r) {   // stage x: 128 nodes x 64 k
                int idx = t + r * 256;
                int node = idx >> 4, k4 = (idx & 15) * 4;
                *(float4*)&sX[node * 68 + k4] =
                    *(const float4*)&x[(nb + node) * IN_CH + k0 + k4];
            }
#pragma unroll
            for (int r = 0; r < 4; ++r) {   // stage W: 64 k x 64 c
                int idx = t + r * 256;
                int k = idx >> 4, c4 = (idx & 15) * 4;
                *(float4*)&sW[k * 64 + c4] = *(const float4*)&W1[(k0 + k) * 64 + c4];
            }
            __syncthreads();
            for (int kk = 0; kk < 64; kk += 4) {
                float4 xv[4];
#pragma unroll
                for (int i = 0; i < 4; ++i)
                    xv[i] = *(float4*)&sX[(tx2 + 32 * i) * 68 + kk];
#pragma unroll
                for (int j = 0; j < 4; ++j) {
                    float4 wa = *(float4*)&sW[(kk + j) * 64 + tc * 8];
                    float4 wb = *(float4*)&sW[(kk + j) * 64 + tc * 8 + 4];
#pragma unroll
                    for (int i = 0; i < 4; ++i) {
                        float xs = ((const float*)&xv[i])[j];
                        acc[i][0] += xs * wa.x; acc[i][1] += xs * wa.y;
                        acc[i][2] += xs * wa.z; acc[i][3] += xs * wa.w;
                        acc[i][4] += xs * wb.x; acc[i][5] += xs * wb.y;
                        acc[i][6] += xs * wb.z; acc[i][7] += xs * wb.w;
                    }
                }
            }
        }
        unsigned int* tab = (tc < 4) ? h1a : h1b;
        int cu = (tc & 3) * 4;
#pragma unroll
        for (int i = 0; i < 4; ++i) {
            long long node = nb + tx2 + 32 * i;
            uint4 pv = {pack2(acc[i][0], acc[i][1]), pack2(acc[i][2], acc[i][3]),
                        pack2(acc[i][4], acc[i][5]), pack2(acc[i][6], acc[i][7])};
            *(uint4*)&tab[node * 16 + cu] = pv;
        }
    }
}

// ---------------- agg layer 1, one 32-feat half per dispatch ----------------
// tab = 5.12 MB table [N][16] uints (feats fbase..fbase+31). Quarter-wave (16
// lanes x uint = 64 B) per edge -> 4 edges in flight per wave, unroll 2.
// h2[n][fbase+f] = relu(dinv[n]*(dinv[n]*t[n][f] + sum_s dinv[s]*t[s][f]) + b1)
__global__ __launch_bounds__(256) void k_agg64h(
        const unsigned int* __restrict__ tab, const int* __restrict__ csr,
        const int* __restrict__ rs_, const int* __restrict__ re_,
        const float* __restrict__ dinv, const float* __restrict__ b1,
        float* __restrict__ h2, int fbase) {
    int n = blockIdx.x * 4 + (threadIdx.x >> 6);
    int lane = threadIdx.x & 63;
    int q = lane >> 4, fo = lane & 15;  // feats fbase+2fo, fbase+2fo+1
    int a = rs_[n], b = re_[n];
    float ax = 0.f, ay = 0.f;
    int e = a + q;
    for (; e + 4 < b; e += 8) {
        int s0 = __builtin_nontemporal_load(&csr[e]);
        int s1 = __builtin_nontemporal_load(&csr[e + 4]);
        unsigned u0 = tab[(size_t)s0 * 16 + fo]; float d0 = dinv[s0];
        unsigned u1 = tab[(size_t)s1 * 16 + fo]; float d1 = dinv[s1];
        ax += d0 * bl(u0); ay += d0 * bh(u0);
        ax += d1 * bl(u1); ay += d1 * bh(u1);
    }
    for (; e < b; e += 4) {
        int s = __builtin_nontemporal_load(&csr[e]);
        unsigned u = tab[(size_t)s * 16 + fo];
        float d = dinv[s];
        ax += d * bl(u); ay += d * bh(u);
    }
    ax += __shfl_down(ax, 32); ay += __shfl_down(ay, 32);
    ax += __shfl_down(ax, 16); ay += __shfl_down(ay, 16);
    if (q == 0) {
        float dn = dinv[n];
        unsigned un = tab[(size_t)n * 16 + fo];
        ax += dn * bl(un); ay += dn * bh(un);   // self loop
        float2 bb = *(const float2*)&b1[fbase + 2 * fo];
        vf2 o = {fmaxf(dn * ax + bb.x, 0.f), fmaxf(dn * ay + bb.y, 0.f)};
        __builtin_nontemporal_store(o, (vf2*)&h2[(size_t)n * 64 + fbase + 2 * fo]);
    }
}

// ---------------- GEMM2: g2[n] = h2[n] @ W2 (UNSCALED), bf16 packed ----------
__global__ __launch_bounds__(256) void k_gemm2(const float* __restrict__ h2,
                                               const float* __restrict__ W2,
                                               unsigned int* __restrict__ g2u) {
    __shared__ float sX[64 * 68];
    __shared__ float sW[64 * 32];
    int t = threadIdx.x;
    long long nb = (long long)blockIdx.x * 64;
    for (int i = t * 4; i < 64 * 32; i += 1024) {
        *(float4*)&sW[i] = *(const float4*)&W2[i];
    }
    for (int r = 0; r < 4; ++r) {
        int n = (t >> 4) + r * 16;
        int k4 = (t & 15) * 4;
        *(float4*)&sX[n * 68 + k4] = *(const float4*)&h2[(nb + n) * HID + k4];
    }
    __syncthreads();
    int tx = t & 7, ty = t >> 3;
    float acc0[4] = {0, 0, 0, 0}, acc1[4] = {0, 0, 0, 0};
#pragma unroll 4
    for (int k = 0; k < 64; ++k) {
        float4 w = *(float4*)&sW[k * 32 + tx * 4];
        float x0 = sX[(ty * 2 + 0) * 68 + k];
        float x1 = sX[(ty * 2 + 1) * 68 + k];
        acc0[0] += x0 * w.x; acc0[1] += x0 * w.y; acc0[2] += x0 * w.z; acc0[3] += x0 * w.w;
        acc1[0] += x1 * w.x; acc1[1] += x1 * w.y; acc1[2] += x1 * w.z; acc1[3] += x1 * w.w;
    }
    long long n = nb + ty * 2;
    uint2 p0 = {pack2(acc0[0], acc0[1]), pack2(acc0[2], acc0[3])};
    *(uint2*)&g2u[n * 16 + tx * 2] = p0;
    uint2 p1 = {pack2(acc1[0], acc1[1]), pack2(acc1[2], acc1[3])};
    *(uint2*)&g2u[(n + 1) * 16 + tx * 2] = p1;
}

// ---------------- agg layer 2: F=32, 5.12 MB table ----------------
// Eighth-wave (8 lanes x uint2 = 64 B) per edge -> 8 edges in flight, unroll 2.
__global__ __launch_bounds__(256) void k_agg32(
        const unsigned int* __restrict__ g2u, const int* __restrict__ csr,
        const int* __restrict__ rs_, const int* __restrict__ re_,
        const float* __restrict__ dinv, const float* __restrict__ b2,
        float* __restrict__ outp) {
    int n = blockIdx.x * 4 + (threadIdx.x >> 6);
    int lane = threadIdx.x & 63;
    int oc = lane >> 3, fo = lane & 7;  // feats 4fo..4fo+3
    int a = rs_[n], b = re_[n];
    float ax = 0.f, ay = 0.f, az = 0.f, aw = 0.f;
    int e = a + oc;
    for (; e + 8 < b; e += 16) {
        int s0 = __builtin_nontemporal_load(&csr[e]);
        int s1 = __builtin_nontemporal_load(&csr[e + 8]);
        uint2 u0 = *(const uint2*)&g2u[(size_t)s0 * 16 + 2 * fo]; float d0 = dinv[s0];
        uint2 u1 = *(const uint2*)&g2u[(size_t)s1 * 16 + 2 * fo]; float d1 = dinv[s1];
        ax += d0 * bl(u0.x); ay += d0 * bh(u0.x);
        az += d0 * bl(u0.y); aw += d0 * bh(u0.y);
        ax += d1 * bl(u1.x); ay += d1 * bh(u1.x);
        az += d1 * bl(u1.y); aw += d1 * bh(u1.y);
    }
    for (; e < b; e += 8) {
        int s = __builtin_nontemporal_load(&csr[e]);
        uint2 u = *(const uint2*)&g2u[(size_t)s * 16 + 2 * fo];
        float d = dinv[s];
        ax += d * bl(u.x); ay += d * bh(u.x);
        az += d * bl(u.y); aw += d * bh(u.y);
    }
    ax += __shfl_down(ax, 32); ay += __shfl_down(ay, 32);
    az += __shfl_down(az, 32); aw += __shfl_down(aw, 32);
    ax += __shfl_down(ax, 16); ay += __shfl_down(ay, 16);
    az += __shfl_down(az, 16); aw += __shfl_down(aw, 16);
    ax += __shfl_down(ax, 8);  ay += __shfl_down(ay, 8);
    az += __shfl_down(az, 8);  aw += __shfl_down(aw, 8);
    if (oc == 0) {
        float dn = dinv[n];
        uint2 un = *(const uint2*)&g2u[(size_t)n * 16 + 2 * fo];
        ax += dn * bl(un.x); ay += dn * bh(un.x);
        az += dn * bl(un.y); aw += dn * bh(un.y);
        float4 bb = *(const float4*)&b2[4 * fo];
        vf4 o = {dn * ax + bb.x, dn * ay + bb.y, dn * az + bb.z, dn * aw + bb.w};
        __builtin_nontemporal_store(o, (vf4*)&outp[(size_t)n * 32 + 4 * fo]);
    }
}

static inline size_t align256(size_t x) { return (x + 255) & ~(size_t)255; }

extern "C" void kernel_launch(void* const* d_in, const int* in_sizes, int n_in,
                              void* d_out, int out_size, void* d_ws, size_t ws_size,
                              hipStream_t stream) {
    const float* x  = (const float*)d_in[0];
    const int*   ei = (const int*)d_in[1];
    const float* W1 = (const float*)d_in[2];
    const float* b1 = (const float*)d_in[3];
    const float* W2 = (const float*)d_in[4];
    const float* b2 = (const float*)d_in[5];
    float* out = (float*)d_out;

    const int* src = ei;
    const int* dst = ei + N_EDGES;

    // workspace layout (peak ~47 MB, proven safe)
    char* ws = (char*)d_ws;
    size_t off = 0;
    int* gcur = (int*)(ws + off);              off = align256(off + NBUCK * 4);
    unsigned int* binned = (unsigned int*)(ws + off);
                                               off = align256(off + (size_t)NBUCK * CAP * 4);
    int* csr = (int*)(ws + off);               off = align256(off + (size_t)NBUCK * CAP * 4);
    int* rs  = (int*)(ws + off);               off = align256(off + (size_t)N_NODES * 4);
    int* re  = (int*)(ws + off);               off = align256(off + (size_t)N_NODES * 4);
    float* dinv = (float*)(ws + off);          off = align256(off + (size_t)N_NODES * 4);
    unsigned int* h1a = (unsigned int*)(ws + off);
                                               off = align256(off + (size_t)N_NODES * 16 * 4);
    unsigned int* h1b = (unsigned int*)(ws + off);
                                               off = align256(off + (size_t)N_NODES * 16 * 4);
    float* h2 = (float*)(ws + off);            off = align256(off + (size_t)N_NODES * HID * 4);
    unsigned int* g2u = h1a;  // reuse; h1a dead after both agg64h passes
                              // (gemm2 writes it only after they complete)

    (void)hipMemsetAsync(gcur, 0, NBUCK * 4, stream);
    k_bin<<<BIN_BLOCKS, 256, 0, stream>>>(src, dst, gcur, binned);
    k_csr_gemm1<<<NBUCK + N_NODES / 128, 256, 0, stream>>>(binned, gcur, csr, rs, re,
                                                           dinv, x, W1, h1a, h1b);
    k_agg64h<<<N_NODES / 4, 256, 0, stream>>>(h1a, csr, rs, re, dinv, b1, h2, 0);
    k_agg64h<<<N_NODES / 4, 256, 0, stream>>>(h1b, csr, rs, re, dinv, b1, h2, 32);
    k_gemm2<<<N_NODES / 64, 256, 0, stream>>>(h2, W2, g2u);
    k_agg32<<<N_NODES / 4, 256, 0, stream>>>(g2u, csr, rs, re, dinv, b2, out);
}

// Round 9
// 249.041 us; speedup vs baseline: 1.0988x; 1.0988x over previous
//
#include <hip/hip_runtime.h>

#define N_NODES 80000
#define N_EDGES 1280000
#define IN_CH 128
#define HID 64
#define OUT_CH 32

#define NBUCK 625      // 128 dst-nodes per bucket; 625*128 == 80000
#define CAP 3072       // bucket capacity; Poisson(mean=2048) -> +20 sigma safe
#define BIN_BLOCKS 256

typedef float vf2 __attribute__((ext_vector_type(2)));
typedef float vf4 __attribute__((ext_vector_type(4)));

// ---- bf16 pack/unpack helpers (RNE) ----
__device__ __forceinline__ float bl(unsigned u) { return __uint_as_float(u << 16); }
__device__ __forceinline__ float bh(unsigned u) { return __uint_as_float(u & 0xFFFF0000u); }
__device__ __forceinline__ unsigned bf16rn(float x) {
    unsigned u = __float_as_uint(x);
    return (u + 0x7FFFu + ((u >> 16) & 1u)) >> 16;
}
__device__ __forceinline__ unsigned pack2(float a, float b) {
    return bf16rn(a) | (bf16rn(b) << 16);
}

// ---------------- pass 1: bin edges by dst bucket ----------------
// packed word: src (17 bits) | dstLocal (7 bits) << 17
__global__ __launch_bounds__(256) void k_bin(const int* __restrict__ src,
                                             const int* __restrict__ dst,
                                             int* __restrict__ gcur,
                                             unsigned int* __restrict__ binned) {
    __shared__ int hist[NBUCK];
    __shared__ int lcur[NBUCK];
    int t = threadIdx.x;
    const int chunk = N_EDGES / BIN_BLOCKS;  // 5000
    int e0 = blockIdx.x * chunk;
    int e1 = e0 + chunk;
    for (int i = t; i < NBUCK; i += 256) hist[i] = 0;
    __syncthreads();
    for (int e = e0 + t; e < e1; e += 256)
        atomicAdd(&hist[dst[e] >> 7], 1);
    __syncthreads();
    for (int i = t; i < NBUCK; i += 256) {
        int h = hist[i];
        lcur[i] = h ? atomicAdd(&gcur[i], h) : 0;
    }
    __syncthreads();
    for (int e = e0 + t; e < e1; e += 256) {
        int d = dst[e];
        int bk = d >> 7;
        int pos = atomicAdd(&lcur[bk], 1);
        if (pos < CAP)
            binned[(size_t)bk * CAP + pos] =
                (unsigned int)src[e] | ((unsigned int)(d & 127) << 17);
    }
}

// ---------------- fused: CSR build (blocks 0..624) + GEMM1 (blocks 625..1249) ----
// CSR: per-bucket counting sort -> csr (src only), rs/re, dinv
// GEMM1: h1[n][:] = x[n] @ W1 (UNSCALED), bf16 packed, single table [N][32] uints
__global__ __launch_bounds__(256) void k_csr_gemm1(
        const unsigned int* __restrict__ binned, const int* __restrict__ cnt,
        int* __restrict__ csr, int* __restrict__ rs, int* __restrict__ re,
        float* __restrict__ dinv,
        const float* __restrict__ x, const float* __restrict__ W1,
        unsigned int* __restrict__ h1u) {
    __shared__ float smem[12800];  // 51200 B: sX 128x68 (8704 f) + sW 64x64 (4096 f)
    int bid = blockIdx.x, t = threadIdx.x;
    if (bid < NBUCK) {
        // ---- CSR path ----
        int* deg = (int*)smem;
        int* scan = deg + 128;
        int* cur = scan + 128;
        int bk = bid;
        int n_e = min(cnt[bk], CAP);
        const unsigned int* eb = binned + (size_t)bk * CAP;
        if (t < 128) deg[t] = 0;
        __syncthreads();
        for (int i = t; i < n_e; i += 256) atomicAdd(&deg[eb[i] >> 17], 1);
        __syncthreads();
        if (t < 128) scan[t] = deg[t];
        __syncthreads();
        for (int off = 1; off < 128; off <<= 1) {
            int v = (t < 128 && t >= off) ? scan[t - off] : 0;
            __syncthreads();
            if (t < 128) scan[t] += v;
            __syncthreads();
        }
        if (t < 128) {
            int incl = scan[t];
            int s = incl - deg[t];
            cur[t] = s;
            int n = bk * 128 + t;
            int base = bk * CAP;
            rs[n] = base + s;
            re[n] = base + incl;
            dinv[n] = rsqrtf((float)(deg[t] + 1));  // +1 self loop
        }
        __syncthreads();
        for (int i = t; i < n_e; i += 256) {
            unsigned int p = eb[i];
            int dL = p >> 17;
            int pos = atomicAdd(&cur[dL], 1);
            csr[bk * CAP + pos] = (int)(p & 0x1FFFF);
        }
    } else {
        // ---- GEMM1 path: 128 nodes/block, 4 nodes x 8 cols per thread ----
        float* sX = smem;             // 128 x 68
        float* sW = smem + 128 * 68;  // 64 x 64
        long long nb = (long long)(bid - NBUCK) * 128;
        int tx2 = t & 31, tc = t >> 5;     // nodes {tx2+32i}, cols tc*8..tc*8+7
        float acc[4][8];
#pragma unroll
        for (int i = 0; i < 4; ++i)
#pragma unroll
            for (int c = 0; c < 8; ++c) acc[i][c] = 0.f;
        for (int H = 0; H < 2; ++H) {
            int k0 = H * 64;
            __syncthreads();
#pragma unroll
            for (int r = 0; r < 8; ++r) {   // stage x: 128 nodes x 64 k
                int idx = t + r * 256;
                int node = idx >> 4, k4 = (idx & 15) * 4;
                *(float4*)&sX[node * 68 + k4] =
                    *(const float4*)&x[(nb + node) * IN_CH + k0 + k4];
            }
#pragma unroll
            for (int r = 0; r < 4; ++r) {   // stage W: 64 k x 64 c
                int idx = t + r * 256;
                int k = idx >> 4, c4 = (idx & 15) * 4;
                *(float4*)&sW[k * 64 + c4] = *(const float4*)&W1[(k0 + k) * 64 + c4];
            }
            __syncthreads();
            for (int kk = 0; kk < 64; kk += 4) {
                float4 xv[4];
#pragma unroll
                for (int i = 0; i < 4; ++i)
                    xv[i] = *(float4*)&sX[(tx2 + 32 * i) * 68 + kk];
#pragma unroll
                for (int j = 0; j < 4; ++j) {
                    float4 wa = *(float4*)&sW[(kk + j) * 64 + tc * 8];
                    float4 wb = *(float4*)&sW[(kk + j) * 64 + tc * 8 + 4];
#pragma unroll
                    for (int i = 0; i < 4; ++i) {
                        float xs = ((const float*)&xv[i])[j];
                        acc[i][0] += xs * wa.x; acc[i][1] += xs * wa.y;
                        acc[i][2] += xs * wa.z; acc[i][3] += xs * wa.w;
                        acc[i][4] += xs * wb.x; acc[i][5] += xs * wb.y;
                        acc[i][6] += xs * wb.z; acc[i][7] += xs * wb.w;
                    }
                }
            }
        }
#pragma unroll
        for (int i = 0; i < 4; ++i) {
            long long node = nb + tx2 + 32 * i;
            uint4 pv = {pack2(acc[i][0], acc[i][1]), pack2(acc[i][2], acc[i][3]),
                        pack2(acc[i][4], acc[i][5]), pack2(acc[i][6], acc[i][7])};
            *(uint4*)&h1u[node * 32 + tc * 4] = pv;
        }
    }
}

// ---------------- agg layer 1 + fused GEMM2 ----------------
// Wave per node: gather-sum dinv[s]*h1[s][:] (full 128 B row per edge, 2 edges
// in flight, unroll 4), epilogue computes relu'd h2 row into per-wave LDS, then
// g2[n][:] = h2row @ W2 (LDS-staged), emitted as bf16 pairs. h2 never hits HBM.
__global__ __launch_bounds__(256) void k_agg64g2(
        const unsigned int* __restrict__ h1u, const int* __restrict__ csr,
        const int* __restrict__ rs_, const int* __restrict__ re_,
        const float* __restrict__ dinv, const float* __restrict__ b1,
        const float* __restrict__ W2, unsigned int* __restrict__ g2u) {
    __shared__ float sW[64 * 32];   // W2, 8 KB
    __shared__ float hrow[4][64];   // per-wave h2 row
    int t = threadIdx.x;
    for (int i = t * 2; i < 64 * 32; i += 512)
        *(float2*)&sW[i] = *(const float2*)&W2[i];
    int wv = t >> 6;
    int n = blockIdx.x * 4 + wv;
    int lane = t & 63;
    int half = lane >> 5, fo = lane & 31;  // feats 2fo, 2fo+1
    int a = rs_[n], b = re_[n];
    float ax = 0.f, ay = 0.f;
    int e = a + half;
    for (; e + 6 < b; e += 8) {
        int s0 = __builtin_nontemporal_load(&csr[e]);
        int s1 = __builtin_nontemporal_load(&csr[e + 2]);
        int s2 = __builtin_nontemporal_load(&csr[e + 4]);
        int s3 = __builtin_nontemporal_load(&csr[e + 6]);
        unsigned u0 = h1u[(size_t)s0 * 32 + fo]; float d0 = dinv[s0];
        unsigned u1 = h1u[(size_t)s1 * 32 + fo]; float d1 = dinv[s1];
        unsigned u2 = h1u[(size_t)s2 * 32 + fo]; float d2 = dinv[s2];
        unsigned u3 = h1u[(size_t)s3 * 32 + fo]; float d3 = dinv[s3];
        ax += d0 * bl(u0); ay += d0 * bh(u0);
        ax += d1 * bl(u1); ay += d1 * bh(u1);
        ax += d2 * bl(u2); ay += d2 * bh(u2);
        ax += d3 * bl(u3); ay += d3 * bh(u3);
    }
    for (; e < b; e += 2) {
        int s = __builtin_nontemporal_load(&csr[e]);
        unsigned u = h1u[(size_t)s * 32 + fo];
        float d = dinv[s];
        ax += d * bl(u); ay += d * bh(u);
    }
    ax += __shfl_down(ax, 32);
    ay += __shfl_down(ay, 32);
    if (half == 0) {
        float dn = dinv[n];
        unsigned un = h1u[(size_t)n * 32 + fo];
        ax += dn * bl(un); ay += dn * bh(un);   // self loop
        float2 bb = *(const float2*)&b1[2 * fo];
        vf2 hv = {fmaxf(dn * ax + bb.x, 0.f), fmaxf(dn * ay + bb.y, 0.f)};
        *(vf2*)&hrow[wv][2 * fo] = hv;
    }
    __syncthreads();   // covers sW staging + hrow writes
    // per-wave GEMM2: lane = col(0..31) + 32*khalf, 32 FMAs each
    int c = lane & 31, kh = lane >> 5;
    float sum = 0.f;
    const float* hr = hrow[wv];
#pragma unroll 8
    for (int i = 0; i < 32; ++i) {
        int k = kh * 32 + i;
        sum += hr[k] * sW[k * 32 + c];
    }
    sum += __shfl_down(sum, 32);       // lanes 0..31 hold full col sums
    float v0 = __shfl(sum, 2 * (lane & 15));
    float v1 = __shfl(sum, 2 * (lane & 15) + 1);
    if (lane < 16)
        g2u[(size_t)n * 16 + lane] = pack2(v0, v1);
}

// ---------------- agg layer 2: F=32, 5.12 MB table ----------------
// Eighth-wave (8 lanes x uint2 = 64 B) per edge -> 8 edges in flight, unroll 2.
__global__ __launch_bounds__(256) void k_agg32(
        const unsigned int* __restrict__ g2u, const int* __restrict__ csr,
        const int* __restrict__ rs_, const int* __restrict__ re_,
        const float* __restrict__ dinv, const float* __restrict__ b2,
        float* __restrict__ outp) {
    int n = blockIdx.x * 4 + (threadIdx.x >> 6);
    int lane = threadIdx.x & 63;
    int oc = lane >> 3, fo = lane & 7;  // feats 4fo..4fo+3
    int a = rs_[n], b = re_[n];
    float ax = 0.f, ay = 0.f, az = 0.f, aw = 0.f;
    int e = a + oc;
    for (; e + 8 < b; e += 16) {
        int s0 = __builtin_nontemporal_load(&csr[e]);
        int s1 = __builtin_nontemporal_load(&csr[e + 8]);
        uint2 u0 = *(const uint2*)&g2u[(size_t)s0 * 16 + 2 * fo]; float d0 = dinv[s0];
        uint2 u1 = *(const uint2*)&g2u[(size_t)s1 * 16 + 2 * fo]; float d1 = dinv[s1];
        ax += d0 * bl(u0.x); ay += d0 * bh(u0.x);
        az += d0 * bl(u0.y); aw += d0 * bh(u0.y);
        ax += d1 * bl(u1.x); ay += d1 * bh(u1.x);
        az += d1 * bl(u1.y); aw += d1 * bh(u1.y);
    }
    for (; e < b; e += 8) {
        int s = __builtin_nontemporal_load(&csr[e]);
        uint2 u = *(const uint2*)&g2u[(size_t)s * 16 + 2 * fo];
        float d = dinv[s];
        ax += d * bl(u.x); ay += d * bh(u.x);
        az += d * bl(u.y); aw += d * bh(u.y);
    }
    ax += __shfl_down(ax, 32); ay += __shfl_down(ay, 32);
    az += __shfl_down(az, 32); aw += __shfl_down(aw, 32);
    ax += __shfl_down(ax, 16); ay += __shfl_down(ay, 16);
    az += __shfl_down(az, 16); aw += __shfl_down(aw, 16);
    ax += __shfl_down(ax, 8);  ay += __shfl_down(ay, 8);
    az += __shfl_down(az, 8);  aw += __shfl_down(aw, 8);
    if (oc == 0) {
        float dn = dinv[n];
        uint2 un = *(const uint2*)&g2u[(size_t)n * 16 + 2 * fo];
        ax += dn * bl(un.x); ay += dn * bh(un.x);
        az += dn * bl(un.y); aw += dn * bh(un.y);
        float4 bb = *(const float4*)&b2[4 * fo];
        vf4 o = {dn * ax + bb.x, dn * ay + bb.y, dn * az + bb.z, dn * aw + bb.w};
        __builtin_nontemporal_store(o, (vf4*)&outp[(size_t)n * 32 + 4 * fo]);
    }
}

static inline size_t align256(size_t x) { return (x + 255) & ~(size_t)255; }

extern "C" void kernel_launch(void* const* d_in, const int* in_sizes, int n_in,
                              void* d_out, int out_size, void* d_ws, size_t ws_size,
                              hipStream_t stream) {
    const float* x  = (const float*)d_in[0];
    const int*   ei = (const int*)d_in[1];
    const float* W1 = (const float*)d_in[2];
    const float* b1 = (const float*)d_in[3];
    const float* W2 = (const float*)d_in[4];
    const float* b2 = (const float*)d_in[5];
    float* out = (float*)d_out;

    const int* src = ei;
    const int* dst = ei + N_EDGES;

    // workspace layout (~32 MB, well under proven 47 MB)
    char* ws = (char*)d_ws;
    size_t off = 0;
    int* gcur = (int*)(ws + off);              off = align256(off + NBUCK * 4);
    unsigned int* binned = (unsigned int*)(ws + off);
                                               off = align256(off + (size_t)NBUCK * CAP * 4);
    int* csr = (int*)(ws + off);               off = align256(off + (size_t)NBUCK * CAP * 4);
    int* rs  = (int*)(ws + off);               off = align256(off + (size_t)N_NODES * 4);
    int* re  = (int*)(ws + off);               off = align256(off + (size_t)N_NODES * 4);
    float* dinv = (float*)(ws + off);          off = align256(off + (size_t)N_NODES * 4);
    unsigned int* h1u = (unsigned int*)(ws + off);
                                               off = align256(off + (size_t)N_NODES * 32 * 4);
    unsigned int* g2u = (unsigned int*)(ws + off);
                                               off = align256(off + (size_t)N_NODES * 16 * 4);

    (void)hipMemsetAsync(gcur, 0, NBUCK * 4, stream);
    k_bin<<<BIN_BLOCKS, 256, 0, stream>>>(src, dst, gcur, binned);
    k_csr_gemm1<<<NBUCK + N_NODES / 128, 256, 0, stream>>>(binned, gcur, csr, rs, re,
                                                           dinv, x, W1, h1u);
    k_agg64g2<<<N_NODES / 4, 256, 0, stream>>>(h1u, csr, rs, re, dinv, b1, W2, g2u);
    k_agg32<<<N_NODES / 4, 256, 0, stream>>>(g2u, csr, rs, re, dinv, b2, out);
}

// Round 10
// 237.063 us; speedup vs baseline: 1.1543x; 1.0505x over previous
//
#include <hip/hip_runtime.h>

#define N_NODES 80000
#define N_EDGES 1280000
#define IN_CH 128
#define HID 64
#define OUT_CH 32

#define NBUCK 625      // 128 dst-nodes per bucket; 625*128 == 80000
#define CAP 3072       // bucket capacity; Poisson(mean=2048) -> +20 sigma safe
#define BIN_BLOCKS 256

typedef float vf2 __attribute__((ext_vector_type(2)));
typedef float vf4 __attribute__((ext_vector_type(4)));

// ---- bf16 pack/unpack helpers (RNE) ----
__device__ __forceinline__ float bl(unsigned u) { return __uint_as_float(u << 16); }
__device__ __forceinline__ float bh(unsigned u) { return __uint_as_float(u & 0xFFFF0000u); }
__device__ __forceinline__ unsigned bf16rn(float x) {
    unsigned u = __float_as_uint(x);
    return (u + 0x7FFFu + ((u >> 16) & 1u)) >> 16;
}
__device__ __forceinline__ unsigned pack2(float a, float b) {
    return bf16rn(a) | (bf16rn(b) << 16);
}

// ---------------- fused K1: bin (blocks 0..255) + GEMM1 (blocks 256..880) ----
// Independent work overlapped in one dispatch: bin is latency/atomic-bound,
// GEMM1 is LDS/VALU-bound; co-residency hides both.
// bin: packed word src | dstLocal<<17 into per-bucket arrays.
// GEMM1: h1[n][:] = x[n] @ W1 (UNSCALED), bf16 packed [N][32] uints.
__global__ __launch_bounds__(256) void k_bin_gemm1(
        const int* __restrict__ src, const int* __restrict__ dst,
        int* __restrict__ gcur, unsigned int* __restrict__ binned,
        const float* __restrict__ x, const float* __restrict__ W1,
        unsigned int* __restrict__ h1u) {
    __shared__ float smem[12800];  // 51200 B
    int bid = blockIdx.x, t = threadIdx.x;
    if (bid < BIN_BLOCKS) {
        // ---- bin path ----
        int* hist = (int*)smem;
        int* lcur = hist + NBUCK;
        const int chunk = N_EDGES / BIN_BLOCKS;  // 5000
        int e0 = bid * chunk;
        int e1 = e0 + chunk;
        for (int i = t; i < NBUCK; i += 256) hist[i] = 0;
        __syncthreads();
        for (int e = e0 + t; e < e1; e += 256)
            atomicAdd(&hist[dst[e] >> 7], 1);
        __syncthreads();
        for (int i = t; i < NBUCK; i += 256) {
            int h = hist[i];
            lcur[i] = h ? atomicAdd(&gcur[i], h) : 0;
        }
        __syncthreads();
        for (int e = e0 + t; e < e1; e += 256) {
            int d = dst[e];
            int bk = d >> 7;
            int pos = atomicAdd(&lcur[bk], 1);
            if (pos < CAP)
                binned[(size_t)bk * CAP + pos] =
                    (unsigned int)src[e] | ((unsigned int)(d & 127) << 17);
        }
    } else {
        // ---- GEMM1 path: 128 nodes/block, 4 nodes x 8 cols per thread ----
        float* sX = smem;             // 128 x 68
        float* sW = smem + 128 * 68;  // 64 x 64
        long long nb = (long long)(bid - BIN_BLOCKS) * 128;
        int tx2 = t & 31, tc = t >> 5;     // nodes {tx2+32i}, cols tc*8..tc*8+7
        float acc[4][8];
#pragma unroll
        for (int i = 0; i < 4; ++i)
#pragma unroll
            for (int c = 0; c < 8; ++c) acc[i][c] = 0.f;
        for (int H = 0; H < 2; ++H) {
            int k0 = H * 64;
            __syncthreads();
#pragma unroll
            for (int r = 0; r < 8; ++r) {   // stage x: 128 nodes x 64 k
                int idx = t + r * 256;
                int node = idx >> 4, k4 = (idx & 15) * 4;
                *(float4*)&sX[node * 68 + k4] =
                    *(const float4*)&x[(nb + node) * IN_CH + k0 + k4];
            }
#pragma unroll
            for (int r = 0; r < 4; ++r) {   // stage W: 64 k x 64 c
                int idx = t + r * 256;
                int k = idx >> 4, c4 = (idx & 15) * 4;
                *(float4*)&sW[k * 64 + c4] = *(const float4*)&W1[(k0 + k) * 64 + c4];
            }
            __syncthreads();
            for (int kk = 0; kk < 64; kk += 4) {
                float4 xv[4];
#pragma unroll
                for (int i = 0; i < 4; ++i)
                    xv[i] = *(float4*)&sX[(tx2 + 32 * i) * 68 + kk];
#pragma unroll
                for (int j = 0; j < 4; ++j) {
                    float4 wa = *(float4*)&sW[(kk + j) * 64 + tc * 8];
                    float4 wb = *(float4*)&sW[(kk + j) * 64 + tc * 8 + 4];
#pragma unroll
                    for (int i = 0; i < 4; ++i) {
                        float xs = ((const float*)&xv[i])[j];
                        acc[i][0] += xs * wa.x; acc[i][1] += xs * wa.y;
                        acc[i][2] += xs * wa.z; acc[i][3] += xs * wa.w;
                        acc[i][4] += xs * wb.x; acc[i][5] += xs * wb.y;
                        acc[i][6] += xs * wb.z; acc[i][7] += xs * wb.w;
                    }
                }
            }
        }
#pragma unroll
        for (int i = 0; i < 4; ++i) {
            long long node = nb + tx2 + 32 * i;
            uint4 pv = {pack2(acc[i][0], acc[i][1]), pack2(acc[i][2], acc[i][3]),
                        pack2(acc[i][4], acc[i][5]), pack2(acc[i][6], acc[i][7])};
            *(uint4*)&h1u[node * 32 + tc * 4] = pv;
        }
    }
}

// ---------------- K2: per-bucket counting sort -> CSR + dinv ----------------
__global__ __launch_bounds__(256) void k_csr(const unsigned int* __restrict__ binned,
                                             const int* __restrict__ cnt,
                                             int* __restrict__ csr,
                                             int* __restrict__ rs, int* __restrict__ re,
                                             float* __restrict__ dinv) {
    __shared__ int deg[128];
    __shared__ int scan[128];
    __shared__ int cur[128];
    int bk = blockIdx.x, t = threadIdx.x;
    int n_e = min(cnt[bk], CAP);
    const unsigned int* eb = binned + (size_t)bk * CAP;
    if (t < 128) deg[t] = 0;
    __syncthreads();
    for (int i = t; i < n_e; i += 256) atomicAdd(&deg[eb[i] >> 17], 1);
    __syncthreads();
    if (t < 128) scan[t] = deg[t];
    __syncthreads();
    for (int off = 1; off < 128; off <<= 1) {
        int v = (t < 128 && t >= off) ? scan[t - off] : 0;
        __syncthreads();
        if (t < 128) scan[t] += v;
        __syncthreads();
    }
    if (t < 128) {
        int incl = scan[t];
        int s = incl - deg[t];
        cur[t] = s;
        int n = bk * 128 + t;
        int base = bk * CAP;
        rs[n] = base + s;
        re[n] = base + incl;
        dinv[n] = rsqrtf((float)(deg[t] + 1));  // +1 self loop
    }
    __syncthreads();
    for (int i = t; i < n_e; i += 256) {
        unsigned int p = eb[i];
        int dL = p >> 17;
        int pos = atomicAdd(&cur[dL], 1);
        csr[bk * CAP + pos] = (int)(p & 0x1FFFF);
    }
}

// ---------------- agg layer 1: F=64, bf16 table, half-wave per edge ----------
// h2[n][f] = relu(dinv[n] * (dinv[n]*h1[n][f] + sum_s dinv[s]*h1[s][f]) + b1[f])
__global__ __launch_bounds__(256) void k_agg64(
        const unsigned int* __restrict__ h1u, const int* __restrict__ csr,
        const int* __restrict__ rs_, const int* __restrict__ re_,
        const float* __restrict__ dinv, const float* __restrict__ b1,
        float* __restrict__ h2) {
    int n = blockIdx.x * 4 + (threadIdx.x >> 6);
    int lane = threadIdx.x & 63;
    int half = lane >> 5, fo = lane & 31;  // feats 2fo, 2fo+1
    int a = rs_[n], b = re_[n];
    float ax = 0.f, ay = 0.f;
    int e = a + half;
    for (; e + 6 < b; e += 8) {
        int s0 = __builtin_nontemporal_load(&csr[e]);
        int s1 = __builtin_nontemporal_load(&csr[e + 2]);
        int s2 = __builtin_nontemporal_load(&csr[e + 4]);
        int s3 = __builtin_nontemporal_load(&csr[e + 6]);
        unsigned u0 = h1u[(size_t)s0 * 32 + fo]; float d0 = dinv[s0];
        unsigned u1 = h1u[(size_t)s1 * 32 + fo]; float d1 = dinv[s1];
        unsigned u2 = h1u[(size_t)s2 * 32 + fo]; float d2 = dinv[s2];
        unsigned u3 = h1u[(size_t)s3 * 32 + fo]; float d3 = dinv[s3];
        ax += d0 * bl(u0); ay += d0 * bh(u0);
        ax += d1 * bl(u1); ay += d1 * bh(u1);
        ax += d2 * bl(u2); ay += d2 * bh(u2);
        ax += d3 * bl(u3); ay += d3 * bh(u3);
    }
    for (; e < b; e += 2) {
        int s = __builtin_nontemporal_load(&csr[e]);
        unsigned u = h1u[(size_t)s * 32 + fo];
        float d = dinv[s];
        ax += d * bl(u); ay += d * bh(u);
    }
    ax += __shfl_down(ax, 32);
    ay += __shfl_down(ay, 32);
    if (half == 0) {
        float dn = dinv[n];
        unsigned un = h1u[(size_t)n * 32 + fo];
        ax += dn * bl(un); ay += dn * bh(un);   // self loop
        float2 bb = *(const float2*)&b1[2 * fo];
        vf2 o = {fmaxf(dn * ax + bb.x, 0.f), fmaxf(dn * ay + bb.y, 0.f)};
        __builtin_nontemporal_store(o, (vf2*)&h2[(size_t)n * 64 + 2 * fo]);
    }
}

// ---------------- GEMM2: g2[n] = h2[n] @ W2 (UNSCALED), bf16 packed ----------
__global__ __launch_bounds__(256) void k_gemm2(const float* __restrict__ h2,
                                               const float* __restrict__ W2,
                                               unsigned int* __restrict__ g2u) {
    __shared__ float sX[64 * 68];
    __shared__ float sW[64 * 32];
    int t = threadIdx.x;
    long long nb = (long long)blockIdx.x * 64;
    for (int i = t * 4; i < 64 * 32; i += 1024) {
        *(float4*)&sW[i] = *(const float4*)&W2[i];
    }
    for (int r = 0; r < 4; ++r) {
        int n = (t >> 4) + r * 16;
        int k4 = (t & 15) * 4;
        *(float4*)&sX[n * 68 + k4] = *(const float4*)&h2[(nb + n) * HID + k4];
    }
    __syncthreads();
    int tx = t & 7, ty = t >> 3;
    float acc0[4] = {0, 0, 0, 0}, acc1[4] = {0, 0, 0, 0};
#pragma unroll 4
    for (int k = 0; k < 64; ++k) {
        float4 w = *(float4*)&sW[k * 32 + tx * 4];
        float x0 = sX[(ty * 2 + 0) * 68 + k];
        float x1 = sX[(ty * 2 + 1) * 68 + k];
        acc0[0] += x0 * w.x; acc0[1] += x0 * w.y; acc0[2] += x0 * w.z; acc0[3] += x0 * w.w;
        acc1[0] += x1 * w.x; acc1[1] += x1 * w.y; acc1[2] += x1 * w.z; acc1[3] += x1 * w.w;
    }
    long long n = nb + ty * 2;
    uint2 p0 = {pack2(acc0[0], acc0[1]), pack2(acc0[2], acc0[3])};
    *(uint2*)&g2u[n * 16 + tx * 2] = p0;
    uint2 p1 = {pack2(acc1[0], acc1[1]), pack2(acc1[2], acc1[3])};
    *(uint2*)&g2u[(n + 1) * 16 + tx * 2] = p1;
}

// ---------------- agg layer 2: F=32, 5.12 MB table ----------------
// Eighth-wave (8 lanes x uint2 = 64 B) per edge -> 8 edges in flight, unroll 2.
__global__ __launch_bounds__(256) void k_agg32(
        const unsigned int* __restrict__ g2u, const int* __restrict__ csr,
        const int* __restrict__ rs_, const int* __restrict__ re_,
        const float* __restrict__ dinv, const float* __restrict__ b2,
        float* __restrict__ outp) {
    int n = blockIdx.x * 4 + (threadIdx.x >> 6);
    int lane = threadIdx.x & 63;
    int oc = lane >> 3, fo = lane & 7;  // feats 4fo..4fo+3
    int a = rs_[n], b = re_[n];
    float ax = 0.f, ay = 0.f, az = 0.f, aw = 0.f;
    int e = a + oc;
    for (; e + 8 < b; e += 16) {
        int s0 = __builtin_nontemporal_load(&csr[e]);
        int s1 = __builtin_nontemporal_load(&csr[e + 8]);
        uint2 u0 = *(const uint2*)&g2u[(size_t)s0 * 16 + 2 * fo]; float d0 = dinv[s0];
        uint2 u1 = *(const uint2*)&g2u[(size_t)s1 * 16 + 2 * fo]; float d1 = dinv[s1];
        ax += d0 * bl(u0.x); ay += d0 * bh(u0.x);
        az += d0 * bl(u0.y); aw += d0 * bh(u0.y);
        ax += d1 * bl(u1.x); ay += d1 * bh(u1.x);
        az += d1 * bl(u1.y); aw += d1 * bh(u1.y);
    }
    for (; e < b; e += 8) {
        int s = __builtin_nontemporal_load(&csr[e]);
        uint2 u = *(const uint2*)&g2u[(size_t)s * 16 + 2 * fo];
        float d = dinv[s];
        ax += d * bl(u.x); ay += d * bh(u.x);
        az += d * bl(u.y); aw += d * bh(u.y);
    }
    ax += __shfl_down(ax, 32); ay += __shfl_down(ay, 32);
    az += __shfl_down(az, 32); aw += __shfl_down(aw, 32);
    ax += __shfl_down(ax, 16); ay += __shfl_down(ay, 16);
    az += __shfl_down(az, 16); aw += __shfl_down(aw, 16);
    ax += __shfl_down(ax, 8);  ay += __shfl_down(ay, 8);
    az += __shfl_down(az, 8);  aw += __shfl_down(aw, 8);
    if (oc == 0) {
        float dn = dinv[n];
        uint2 un = *(const uint2*)&g2u[(size_t)n * 16 + 2 * fo];
        ax += dn * bl(un.x); ay += dn * bh(un.x);
        az += dn * bl(un.y); aw += dn * bh(un.y);
        float4 bb = *(const float4*)&b2[4 * fo];
        vf4 o = {dn * ax + bb.x, dn * ay + bb.y, dn * az + bb.z, dn * aw + bb.w};
        __builtin_nontemporal_store(o, (vf4*)&outp[(size_t)n * 32 + 4 * fo]);
    }
}

static inline size_t align256(size_t x) { return (x + 255) & ~(size_t)255; }

extern "C" void kernel_launch(void* const* d_in, const int* in_sizes, int n_in,
                              void* d_out, int out_size, void* d_ws, size_t ws_size,
                              hipStream_t stream) {
    const float* x  = (const float*)d_in[0];
    const int*   ei = (const int*)d_in[1];
    const float* W1 = (const float*)d_in[2];
    const float* b1 = (const float*)d_in[3];
    const float* W2 = (const float*)d_in[4];
    const float* b2 = (const float*)d_in[5];
    float* out = (float*)d_out;

    const int* src = ei;
    const int* dst = ei + N_EDGES;

    // workspace layout (~37 MB, under proven 47 MB)
    char* ws = (char*)d_ws;
    size_t off = 0;
    int* gcur = (int*)(ws + off);              off = align256(off + NBUCK * 4);
    unsigned int* binned = (unsigned int*)(ws + off);
                                               off = align256(off + (size_t)NBUCK * CAP * 4);
    int* csr = (int*)(ws + off);               off = align256(off + (size_t)NBUCK * CAP * 4);
    int* rs  = (int*)(ws + off);               off = align256(off + (size_t)N_NODES * 4);
    int* re  = (int*)(ws + off);               off = align256(off + (size_t)N_NODES * 4);
    float* dinv = (float*)(ws + off);          off = align256(off + (size_t)N_NODES * 4);
    unsigned int* h1u = (unsigned int*)(ws + off);
                                               off = align256(off + (size_t)N_NODES * 32 * 4);
    float* h2 = (float*)(ws + off);            off = align256(off + (size_t)N_NODES * HID * 4);
    unsigned int* g2u = h1u;  // reuse; h1u dead after agg64 (gemm2 runs after)

    (void)hipMemsetAsync(gcur, 0, NBUCK * 4, stream);
    k_bin_gemm1<<<BIN_BLOCKS + N_NODES / 128, 256, 0, stream>>>(src, dst, gcur, binned,
                                                                x, W1, h1u);
    k_csr<<<NBUCK, 256, 0, stream>>>(binned, gcur, csr, rs, re, dinv);
    k_agg64<<<N_NODES / 4, 256, 0, stream>>>(h1u, csr, rs, re, dinv, b1, h2);
    k_gemm2<<<N_NODES / 64, 256, 0, stream>>>(h2, W2, g2u);
    k_agg32<<<N_NODES / 4, 256, 0, stream>>>(g2u, csr, rs, re, dinv, b2, out);
}

// Round 11
// 219.199 us; speedup vs baseline: 1.2484x; 1.0815x over previous
//
#include <hip/hip_runtime.h>
#include <hip/hip_fp16.h>

#define N_NODES 80000
#define N_EDGES 1280000
#define IN_CH 128
#define HID 64
#define OUT_CH 32

#define NBUCK 625      // 128 dst-nodes per bucket; 625*128 == 80000
#define CAP 3072       // bucket capacity; Poisson(mean=2048) -> +20 sigma safe
#define BIN_BLOCKS 256

typedef float vf2 __attribute__((ext_vector_type(2)));
typedef float vf4 __attribute__((ext_vector_type(4)));
typedef short short8 __attribute__((ext_vector_type(8)));   // 8 bf16 (4 VGPRs)
typedef float floatx4 __attribute__((ext_vector_type(4)));  // MFMA acc

// ---- bf16 pack (RNE) for MFMA staging ----
__device__ __forceinline__ unsigned bf16rn(float x) {
    unsigned u = __float_as_uint(x);
    return (u + 0x7FFFu + ((u >> 16) & 1u)) >> 16;
}
__device__ __forceinline__ unsigned packbf2(float a, float b) {
    return bf16rn(a) | (bf16rn(b) << 16);
}
// ---- f16 pack/unpack for gather tables ----
__device__ __forceinline__ float hl(unsigned u) {
    return __half2float(__ushort_as_half((unsigned short)(u & 0xFFFFu)));
}
__device__ __forceinline__ float hh(unsigned u) {
    return __half2float(__ushort_as_half((unsigned short)(u >> 16)));
}
__device__ __forceinline__ unsigned pack2h(float a, float b) {
    return (unsigned)__half_as_ushort(__float2half_rn(a)) |
           ((unsigned)__half_as_ushort(__float2half_rn(b)) << 16);
}

// ---------------- fused K1: bin (blocks 0..255) + MFMA GEMM1 (blocks 256..880) ----
// bin: packed word src | dstLocal<<17 into per-bucket arrays.
// GEMM1: h1[n][:] = x[n] @ W1 (UNSCALED), f16 table [N][64] ushort.
// MFMA 16x16x32 bf16: per wave 32 nodes x 64 cols, K=128 in 4 steps.
__global__ __launch_bounds__(256) void k_bin_gemm1(
        const int* __restrict__ src, const int* __restrict__ dst,
        int* __restrict__ gcur, unsigned int* __restrict__ binned,
        const float* __restrict__ x, const float* __restrict__ W1,
        unsigned short* __restrict__ h1h) {
    __shared__ unsigned short smem_u[26112];  // 52224 B
    int bid = blockIdx.x, t = threadIdx.x;
    if (bid < BIN_BLOCKS) {
        // ---- bin path ----
        int* hist = (int*)smem_u;
        int* lcur = hist + NBUCK;
        const int chunk = N_EDGES / BIN_BLOCKS;  // 5000
        int e0 = bid * chunk;
        int e1 = e0 + chunk;
        for (int i = t; i < NBUCK; i += 256) hist[i] = 0;
        __syncthreads();
        for (int e = e0 + t; e < e1; e += 256)
            atomicAdd(&hist[dst[e] >> 7], 1);
        __syncthreads();
        for (int i = t; i < NBUCK; i += 256) {
            int h = hist[i];
            lcur[i] = h ? atomicAdd(&gcur[i], h) : 0;
        }
        __syncthreads();
        for (int e = e0 + t; e < e1; e += 256) {
            int d = dst[e];
            int bk = d >> 7;
            int pos = atomicAdd(&lcur[bk], 1);
            if (pos < CAP)
                binned[(size_t)bk * CAP + pos] =
                    (unsigned int)src[e] | ((unsigned int)(d & 127) << 17);
        }
    } else {
        // ---- MFMA GEMM1: sX [128 nodes][136] bf16, sWT [64 cols][136] bf16 ----
        unsigned short* sX = smem_u;              // 128*136
        unsigned short* sWT = smem_u + 128 * 136; // 64*136
        long long nb = (long long)(bid - BIN_BLOCKS) * 128;
        // stage x -> bf16 (row-major, k contiguous)
        for (int it = 0; it < 16; ++it) {
            int idx = t + it * 256;               // 4096 float4 loads
            int node = idx >> 5, k4 = (idx & 31) * 4;
            float4 v = *(const float4*)&x[(nb + node) * IN_CH + k4];
            unsigned u0 = packbf2(v.x, v.y), u1 = packbf2(v.z, v.w);
            *(uint2*)&sX[node * 136 + k4] = (uint2){u0, u1};
        }
        // stage W1^T -> bf16 ([col][k])
        for (int it = 0; it < 8; ++it) {
            int idx = t + it * 256;               // 2048 float4 loads
            int k = idx >> 4, c4 = (idx & 15) * 4;
            float4 w = *(const float4*)&W1[k * 64 + c4];
            sWT[(c4 + 0) * 136 + k] = (unsigned short)bf16rn(w.x);
            sWT[(c4 + 1) * 136 + k] = (unsigned short)bf16rn(w.y);
            sWT[(c4 + 2) * 136 + k] = (unsigned short)bf16rn(w.z);
            sWT[(c4 + 3) * 136 + k] = (unsigned short)bf16rn(w.w);
        }
        __syncthreads();
        int wv = t >> 6, lane = t & 63;
        int lm = lane & 15, q = lane >> 4;
        int m0 = wv * 32;
        floatx4 acc[2][4];
#pragma unroll
        for (int i = 0; i < 2; ++i)
#pragma unroll
            for (int j = 0; j < 4; ++j) acc[i][j] = (floatx4){0.f, 0.f, 0.f, 0.f};
#pragma unroll
        for (int kk = 0; kk < 128; kk += 32) {
            short8 a0 = *(short8*)&sX[(m0 + lm) * 136 + kk + q * 8];
            short8 a1 = *(short8*)&sX[(m0 + 16 + lm) * 136 + kk + q * 8];
#pragma unroll
            for (int ct = 0; ct < 4; ++ct) {
                short8 bfr = *(short8*)&sWT[(ct * 16 + lm) * 136 + kk + q * 8];
                acc[0][ct] = __builtin_amdgcn_mfma_f32_16x16x32_bf16(a0, bfr, acc[0][ct], 0, 0, 0);
                acc[1][ct] = __builtin_amdgcn_mfma_f32_16x16x32_bf16(a1, bfr, acc[1][ct], 0, 0, 0);
            }
        }
        // D layout: col = lane&15, row = q*4 + reg
#pragma unroll
        for (int mt = 0; mt < 2; ++mt)
#pragma unroll
            for (int ct = 0; ct < 4; ++ct)
#pragma unroll
                for (int r = 0; r < 4; ++r) {
                    long long node = nb + m0 + mt * 16 + q * 4 + r;
                    int c = ct * 16 + lm;
                    h1h[node * 64 + c] = __half_as_ushort(__float2half_rn(acc[mt][ct][r]));
                }
    }
}

// ---------------- K2: per-bucket counting sort -> CSR + dinv ----------------
__global__ __launch_bounds__(256) void k_csr(const unsigned int* __restrict__ binned,
                                             const int* __restrict__ cnt,
                                             int* __restrict__ csr,
                                             int* __restrict__ rs, int* __restrict__ re,
                                             float* __restrict__ dinv) {
    __shared__ int deg[128];
    __shared__ int scan[128];
    __shared__ int cur[128];
    int bk = blockIdx.x, t = threadIdx.x;
    int n_e = min(cnt[bk], CAP);
    const unsigned int* eb = binned + (size_t)bk * CAP;
    if (t < 128) deg[t] = 0;
    __syncthreads();
    for (int i = t; i < n_e; i += 256) atomicAdd(&deg[eb[i] >> 17], 1);
    __syncthreads();
    if (t < 128) scan[t] = deg[t];
    __syncthreads();
    for (int off = 1; off < 128; off <<= 1) {
        int v = (t < 128 && t >= off) ? scan[t - off] : 0;
        __syncthreads();
        if (t < 128) scan[t] += v;
        __syncthreads();
    }
    if (t < 128) {
        int incl = scan[t];
        int s = incl - deg[t];
        cur[t] = s;
        int n = bk * 128 + t;
        int base = bk * CAP;
        rs[n] = base + s;
        re[n] = base + incl;
        dinv[n] = rsqrtf((float)(deg[t] + 1));  // +1 self loop
    }
    __syncthreads();
    for (int i = t; i < n_e; i += 256) {
        unsigned int p = eb[i];
        int dL = p >> 17;
        int pos = atomicAdd(&cur[dL], 1);
        csr[bk * CAP + pos] = (int)(p & 0x1FFFF);
    }
}

// ---------------- agg layer 1: F=64, f16 table, half-wave per edge ----------
// h2[n][f] = relu(dinv[n] * (dinv[n]*h1[n][f] + sum_s dinv[s]*h1[s][f]) + b1[f])
__global__ __launch_bounds__(256) void k_agg64(
        const unsigned int* __restrict__ h1u, const int* __restrict__ csr,
        const int* __restrict__ rs_, const int* __restrict__ re_,
        const float* __restrict__ dinv, const float* __restrict__ b1,
        float* __restrict__ h2) {
    int n = blockIdx.x * 4 + (threadIdx.x >> 6);
    int lane = threadIdx.x & 63;
    int half = lane >> 5, fo = lane & 31;  // feats 2fo, 2fo+1
    int a = rs_[n], b = re_[n];
    float ax = 0.f, ay = 0.f;
    int e = a + half;
    for (; e + 6 < b; e += 8) {
        int s0 = csr[e], s1 = csr[e + 2], s2 = csr[e + 4], s3 = csr[e + 6];
        unsigned u0 = h1u[(size_t)s0 * 32 + fo]; float d0 = dinv[s0];
        unsigned u1 = h1u[(size_t)s1 * 32 + fo]; float d1 = dinv[s1];
        unsigned u2 = h1u[(size_t)s2 * 32 + fo]; float d2 = dinv[s2];
        unsigned u3 = h1u[(size_t)s3 * 32 + fo]; float d3 = dinv[s3];
        ax += d0 * hl(u0); ay += d0 * hh(u0);
        ax += d1 * hl(u1); ay += d1 * hh(u1);
        ax += d2 * hl(u2); ay += d2 * hh(u2);
        ax += d3 * hl(u3); ay += d3 * hh(u3);
    }
    for (; e < b; e += 2) {
        int s = csr[e];
        unsigned u = h1u[(size_t)s * 32 + fo];
        float d = dinv[s];
        ax += d * hl(u); ay += d * hh(u);
    }
    ax += __shfl_down(ax, 32);
    ay += __shfl_down(ay, 32);
    if (half == 0) {
        float dn = dinv[n];
        unsigned un = h1u[(size_t)n * 32 + fo];
        ax += dn * hl(un); ay += dn * hh(un);   // self loop
        float2 bb = *(const float2*)&b1[2 * fo];
        float2 o = {fmaxf(dn * ax + bb.x, 0.f), fmaxf(dn * ay + bb.y, 0.f)};
        *(float2*)&h2[(size_t)n * 64 + 2 * fo] = o;
    }
}

// ---------------- GEMM2: g2[n] = h2[n] @ W2 (UNSCALED), f16 packed ----------
__global__ __launch_bounds__(256) void k_gemm2(const float* __restrict__ h2,
                                               const float* __restrict__ W2,
                                               unsigned int* __restrict__ g2u) {
    __shared__ float sX[64 * 68];
    __shared__ float sW[64 * 32];
    int t = threadIdx.x;
    long long nb = (long long)blockIdx.x * 64;
    for (int i = t * 4; i < 64 * 32; i += 1024) {
        *(float4*)&sW[i] = *(const float4*)&W2[i];
    }
    for (int r = 0; r < 4; ++r) {
        int n = (t >> 4) + r * 16;
        int k4 = (t & 15) * 4;
        *(float4*)&sX[n * 68 + k4] = *(const float4*)&h2[(nb + n) * HID + k4];
    }
    __syncthreads();
    int tx = t & 7, ty = t >> 3;
    float acc0[4] = {0, 0, 0, 0}, acc1[4] = {0, 0, 0, 0};
#pragma unroll 4
    for (int k = 0; k < 64; ++k) {
        float4 w = *(float4*)&sW[k * 32 + tx * 4];
        float x0 = sX[(ty * 2 + 0) * 68 + k];
        float x1 = sX[(ty * 2 + 1) * 68 + k];
        acc0[0] += x0 * w.x; acc0[1] += x0 * w.y; acc0[2] += x0 * w.z; acc0[3] += x0 * w.w;
        acc1[0] += x1 * w.x; acc1[1] += x1 * w.y; acc1[2] += x1 * w.z; acc1[3] += x1 * w.w;
    }
    long long n = nb + ty * 2;
    uint2 p0 = {pack2h(acc0[0], acc0[1]), pack2h(acc0[2], acc0[3])};
    *(uint2*)&g2u[n * 16 + tx * 2] = p0;
    uint2 p1 = {pack2h(acc1[0], acc1[1]), pack2h(acc1[2], acc1[3])};
    *(uint2*)&g2u[(n + 1) * 16 + tx * 2] = p1;
}

// ---------------- agg layer 2: F=32, f16 table ----------------
// Eighth-wave (8 lanes x uint2 = 64 B) per edge -> 8 edges in flight, unroll 2.
__global__ __launch_bounds__(256) void k_agg32(
        const unsigned int* __restrict__ g2u, const int* __restrict__ csr,
        const int* __restrict__ rs_, const int* __restrict__ re_,
        const float* __restrict__ dinv, const float* __restrict__ b2,
        float* __restrict__ outp) {
    int n = blockIdx.x * 4 + (threadIdx.x >> 6);
    int lane = threadIdx.x & 63;
    int oc = lane >> 3, fo = lane & 7;  // feats 4fo..4fo+3
    int a = rs_[n], b = re_[n];
    float ax = 0.f, ay = 0.f, az = 0.f, aw = 0.f;
    int e = a + oc;
    for (; e + 8 < b; e += 16) {
        int s0 = csr[e], s1 = csr[e + 8];
        uint2 u0 = *(const uint2*)&g2u[(size_t)s0 * 16 + 2 * fo]; float d0 = dinv[s0];
        uint2 u1 = *(const uint2*)&g2u[(size_t)s1 * 16 + 2 * fo]; float d1 = dinv[s1];
        ax += d0 * hl(u0.x); ay += d0 * hh(u0.x);
        az += d0 * hl(u0.y); aw += d0 * hh(u0.y);
        ax += d1 * hl(u1.x); ay += d1 * hh(u1.x);
        az += d1 * hl(u1.y); aw += d1 * hh(u1.y);
    }
    for (; e < b; e += 8) {
        int s = csr[e];
        uint2 u = *(const uint2*)&g2u[(size_t)s * 16 + 2 * fo];
        float d = dinv[s];
        ax += d * hl(u.x); ay += d * hh(u.x);
        az += d * hl(u.y); aw += d * hh(u.y);
    }
    ax += __shfl_down(ax, 32); ay += __shfl_down(ay, 32);
    az += __shfl_down(az, 32); aw += __shfl_down(aw, 32);
    ax += __shfl_down(ax, 16); ay += __shfl_down(ay, 16);
    az += __shfl_down(az, 16); aw += __shfl_down(aw, 16);
    ax += __shfl_down(ax, 8);  ay += __shfl_down(ay, 8);
    az += __shfl_down(az, 8);  aw += __shfl_down(aw, 8);
    if (oc == 0) {
        float dn = dinv[n];
        uint2 un = *(const uint2*)&g2u[(size_t)n * 16 + 2 * fo];
        ax += dn * hl(un.x); ay += dn * hh(un.x);
        az += dn * hl(un.y); aw += dn * hh(un.y);
        float4 bb = *(const float4*)&b2[4 * fo];
        vf4 o = {dn * ax + bb.x, dn * ay + bb.y, dn * az + bb.z, dn * aw + bb.w};
        __builtin_nontemporal_store(o, (vf4*)&outp[(size_t)n * 32 + 4 * fo]);
    }
}

static inline size_t align256(size_t x) { return (x + 255) & ~(size_t)255; }

extern "C" void kernel_launch(void* const* d_in, const int* in_sizes, int n_in,
                              void* d_out, int out_size, void* d_ws, size_t ws_size,
                              hipStream_t stream) {
    const float* x  = (const float*)d_in[0];
    const int*   ei = (const int*)d_in[1];
    const float* W1 = (const float*)d_in[2];
    const float* b1 = (const float*)d_in[3];
    const float* W2 = (const float*)d_in[4];
    const float* b2 = (const float*)d_in[5];
    float* out = (float*)d_out;

    const int* src = ei;
    const int* dst = ei + N_EDGES;

    // workspace layout (~37 MB, under proven 47 MB)
    char* ws = (char*)d_ws;
    size_t off = 0;
    int* gcur = (int*)(ws + off);              off = align256(off + NBUCK * 4);
    unsigned int* binned = (unsigned int*)(ws + off);
                                               off = align256(off + (size_t)NBUCK * CAP * 4);
    int* csr = (int*)(ws + off);               off = align256(off + (size_t)NBUCK * CAP * 4);
    int* rs  = (int*)(ws + off);               off = align256(off + (size_t)N_NODES * 4);
    int* re  = (int*)(ws + off);               off = align256(off + (size_t)N_NODES * 4);
    float* dinv = (float*)(ws + off);          off = align256(off + (size_t)N_NODES * 4);
    unsigned short* h1h = (unsigned short*)(ws + off);
                                               off = align256(off + (size_t)N_NODES * 64 * 2);
    float* h2 = (float*)(ws + off);            off = align256(off + (size_t)N_NODES * HID * 4);
    unsigned int* g2u = (unsigned int*)h1h;  // reuse; h1h dead after agg64

    (void)hipMemsetAsync(gcur, 0, NBUCK * 4, stream);
    k_bin_gemm1<<<BIN_BLOCKS + N_NODES / 128, 256, 0, stream>>>(src, dst, gcur, binned,
                                                                x, W1, h1h);
    k_csr<<<NBUCK, 256, 0, stream>>>(binned, gcur, csr, rs, re, dinv);
    k_agg64<<<N_NODES / 4, 256, 0, stream>>>((const unsigned int*)h1h, csr, rs, re,
                                             dinv, b1, h2);
    k_gemm2<<<N_NODES / 64, 256, 0, stream>>>(h2, W2, g2u);
    k_agg32<<<N_NODES / 4, 256, 0, stream>>>(g2u, csr, rs, re, dinv, b2, out);
}